// Round 4
// baseline (64.389 us; speedup 1.0000x reference)
//
#include <hip/hip_runtime.h>

constexpr int    NN      = 8192;
constexpr float  MARGIN  = 0.01f;
constexpr int    TT      = 128;                 // tile side == threads per block
constexpr int    NT      = NN / TT;             // 64
constexpr int    NBLOCKS = NT * (NT + 1) / 2;   // 2080 (upper triangle incl diag)
constexpr int    PREP_BLOCKS = NN / 256;        // 32

// d_ws layout (bytes):
//   [0]      unsigned int counter     (reset by prep each call)
//   [256]    double price_part[32]
//   [512]    double rank_part[2080]
//   [32768]  float2 r2[8192]          {pred_r, act_r}

__global__ __launch_bounds__(256)
void prep_kernel(const float* __restrict__ pred,
                 const float* __restrict__ act,
                 const float* __restrict__ prev,
                 float2* __restrict__ r2,
                 double* __restrict__ price_part,
                 unsigned int* __restrict__ counter)
{
    const int g  = blockIdx.x * 256 + threadIdx.x;
    const float pv = prev[g];
    const float p  = pred[g];
    const float a  = act[g];
    r2[g] = make_float2((p - pv) / pv, (a - pv) / pv);

    const float d  = p - a;
    double pp = (double)(d * d);
    for (int off = 32; off > 0; off >>= 1) pp += __shfl_down(pp, off, 64);
    __shared__ double red[4];
    if ((threadIdx.x & 63) == 0) red[threadIdx.x >> 6] = pp;
    __syncthreads();
    if (threadIdx.x == 0) {
        price_part[blockIdx.x] = red[0] + red[1] + red[2] + red[3];
        if (blockIdx.x == 0) *counter = 0u;   // stream-ordered before pair_kernel
    }
}

// Sum of hinge over tiles of the upper triangle (incl. diagonal tile).
// Off-diagonal tiles doubled (hinge symmetric); diagonal tiles process both
// orders once each; i==j slots contribute exactly MARGIN -> subtracted
// analytically. count = NN*(NN-1) (continuous data: no off-diagonal ties).
__global__ __launch_bounds__(TT)
void pair_kernel(const float2* __restrict__ r2,
                 double* __restrict__ rank_part,
                 const double* __restrict__ price_part,
                 unsigned int* __restrict__ counter,
                 float* __restrict__ out)
{
    const int t = blockIdx.x;
    // triangle decode: row ib has (NT - ib) tiles; OFF(r) = r*(2*NT+1-r)/2
    // disc = (2*NT+1)^2 - 8*t ; perfect square at row starts -> exact sqrtf
    int ib = (int)((129.0f - sqrtf(16641.0f - 8.0f * (float)t)) * 0.5f);
#define OFF(r) ((r) * (129 - (r)) / 2)
    while (OFF(ib + 1) <= t) ++ib;   // safety fixups (at most one step)
    while (OFF(ib) > t) --ib;
    const int jc = ib + (t - OFF(ib));
#undef OFF

    const int tid = threadIdx.x;
    __shared__ alignas(16) float2 s_t[TT];
    s_t[tid] = r2[jc * TT + tid];
    const float2 ri = r2[ib * TT + tid];
    __syncthreads();

    const float pri = ri.x;
    const float ari = ri.y;

    float a0 = 0.f, a1 = 0.f, a2 = 0.f, a3 = 0.f;
    const float4* __restrict__ s4 = (const float4*)s_t;

#define PAIR(pj, aj, acc)                                  \
    {                                                      \
        const float ad = ari - (aj);                       \
        const float pd = pri - (pj);                       \
        const float u  = (ad > 0.0f) ? -pd : pd;           \
        acc += fmaxf(0.0f, MARGIN + u);                    \
    }

#pragma unroll 8
    for (int g = 0; g < TT / 2; g += 2) {
        const float4 q0 = s4[g];
        const float4 q1 = s4[g + 1];
        PAIR(q0.x, q0.y, a0);
        PAIR(q0.z, q0.w, a1);
        PAIR(q1.x, q1.y, a2);
        PAIR(q1.z, q1.w, a3);
    }
#undef PAIR

    double ws = (double)((a0 + a1) + (a2 + a3));
    if (jc != ib) ws += ws;                    // off-diagonal tile -> both orders

    for (int off = 32; off > 0; off >>= 1) ws += __shfl_down(ws, off, 64);

    __shared__ double red[2];
    __shared__ bool   lastf;
    if ((tid & 63) == 0) red[tid >> 6] = ws;
    __syncthreads();
    if (tid == 0) {
        rank_part[t] = red[0] + red[1];
        const unsigned tk = __hip_atomic_fetch_add(counter, 1u, __ATOMIC_ACQ_REL,
                                                   __HIP_MEMORY_SCOPE_AGENT);
        lastf = (tk == (unsigned)(NBLOCKS - 1));
    }
    __syncthreads();
    if (!lastf) return;

    // last block: final reduction
    double s = 0.0, p = 0.0;
    for (int k = tid; k < NBLOCKS; k += TT) s += rank_part[k];
    for (int k = tid; k < PREP_BLOCKS; k += TT) p += price_part[k];
    for (int off = 32; off > 0; off >>= 1) {
        s += __shfl_down(s, off, 64);
        p += __shfl_down(p, off, 64);
    }
    __shared__ double rs2[2], rp2[2];
    if ((tid & 63) == 0) { rs2[tid >> 6] = s; rp2[tid >> 6] = p; }
    __syncthreads();
    if (tid == 0) {
        const double S = rs2[0] + rs2[1];
        const double P = rp2[0] + rp2[1];
        const double rank = (S - (double)NN * (double)MARGIN)
                          / ((double)NN * (double)(NN - 1));
        out[0] = (float)(0.5 * (P / (double)NN) + 0.5 * rank);
    }
}

extern "C" void kernel_launch(void* const* d_in, const int* in_sizes, int n_in,
                              void* d_out, int out_size, void* d_ws, size_t ws_size,
                              hipStream_t stream)
{
    const float* pred = (const float*)d_in[0];
    const float* act  = (const float*)d_in[1];
    const float* prev = (const float*)d_in[2];

    char* w = (char*)d_ws;
    unsigned int* counter    = (unsigned int*)(w + 0);
    double*       price_part = (double*)(w + 256);
    double*       rank_part  = (double*)(w + 512);
    float2*       r2         = (float2*)(w + 32768);

    prep_kernel<<<PREP_BLOCKS, 256, 0, stream>>>(pred, act, prev, r2, price_part, counter);
    pair_kernel<<<NBLOCKS, TT, 0, stream>>>(r2, rank_part, price_part, counter, (float*)d_out);
}

// Round 5
// 15.686 us; speedup vs baseline: 4.1050x; 4.1050x over previous
//
#include <hip/hip_runtime.h>

constexpr int    NN     = 8192;
constexpr float  MARGIN = 0.01f;
constexpr int    TI     = 256;           // i-rows per block == threads
constexpr int    TJ     = 128;           // j-chunk per block
constexpr int    NTI    = NN / TI;       // 32
constexpr int    NTJ    = NN / TJ;       // 64
constexpr int    NBLOCKS = NTJ * NTI - NTI * (NTI - 1); // 1056

// Symmetry: hinge(i,j)==hinge(j,i). Row-tile ib vs j-chunks jc in [2ib, 64):
// jc in {2ib, 2ib+1} = inside the 256x256 diagonal tile -> each ordered pair
// once, no doubling. jc >= 2ib+2 -> strictly upper tiles, doubled.
// Diagonal slots i==j contribute exactly MARGIN each (ad=0 -> s=+1, pd=0);
// subtracted analytically. count = NN*(NN-1) (continuous data, no ties;
// validated absmax==0 in rounds 3-4).
__global__ __launch_bounds__(TI)
void pair_kernel(const float* __restrict__ pred,
                 const float* __restrict__ act,
                 const float* __restrict__ prev,
                 double* __restrict__ partials)   // [NBLOCKS][2]: rank, price
{
    // decode flat block id -> (ib, jc); row ib has (NTJ - 2*ib) j-chunks
    int t  = blockIdx.x;
    int ib = 0;
    while (t >= NTJ - 2 * ib) { t -= NTJ - 2 * ib; ++ib; }
    const int  jc        = 2 * ib + t;
    const bool diag_like = (t < 2);
    const bool do_price  = (t == 0);

    __shared__ float2 s_t[TJ];

    const int tid = threadIdx.x;
    if (tid < TJ) {
        const int   j  = jc * TJ + tid;
        const float pv = prev[j];
        s_t[tid] = make_float2((pred[j] - pv) / pv, (act[j] - pv) / pv);
    }

    const int   i   = ib * TI + tid;
    const float pv  = prev[i];
    const float pri = (pred[i] - pv) / pv;
    const float ari = (act[i]  - pv) / pv;

    double pp = 0.0;
    if (do_price) {
        const float d = pred[i] - act[i];
        pp = (double)(d * d);
    }

    __syncthreads();

    float a0 = 0.f, a1 = 0.f, a2 = 0.f, a3 = 0.f;

#define PAIR(tv, acc)                                       \
    {                                                       \
        const float ad = ari - (tv).y;                      \
        const float pd = pri - (tv).x;                      \
        const float s  = (ad > 0.0f) ? -1.0f : 1.0f;        \
        acc += fmaxf(0.0f, fmaf(s, pd, MARGIN));            \
    }

#pragma unroll 8
    for (int j = 0; j < TJ; j += 4) {
        const float2 t0 = s_t[j + 0];
        const float2 t1 = s_t[j + 1];
        const float2 t2 = s_t[j + 2];
        const float2 t3 = s_t[j + 3];
        PAIR(t0, a0);
        PAIR(t1, a1);
        PAIR(t2, a2);
        PAIR(t3, a3);
    }
#undef PAIR

    double ws = (double)((a0 + a1) + (a2 + a3));
    if (!diag_like) ws += ws;

    // wave-64 butterfly
    for (int off = 32; off > 0; off >>= 1) {
        ws += __shfl_down(ws, off, 64);
        pp += __shfl_down(pp, off, 64);
    }

    __shared__ double rs[4], rp[4];
    const int w = tid >> 6;
    if ((tid & 63) == 0) { rs[w] = ws; rp[w] = pp; }
    __syncthreads();
    if (tid == 0) {
        partials[2 * blockIdx.x + 0] = rs[0] + rs[1] + rs[2] + rs[3];
        partials[2 * blockIdx.x + 1] = rp[0] + rp[1] + rp[2] + rp[3];
    }
}

__global__ __launch_bounds__(256)
void finalize_kernel(const double* __restrict__ partials,
                     float* __restrict__ out)
{
    double s = 0.0, p = 0.0;
    for (int t = threadIdx.x; t < NBLOCKS; t += 256) {
        s += partials[2 * t + 0];
        p += partials[2 * t + 1];
    }
    for (int off = 32; off > 0; off >>= 1) {
        s += __shfl_down(s, off, 64);
        p += __shfl_down(p, off, 64);
    }
    __shared__ double rs[4], rp[4];
    const int w = threadIdx.x >> 6;
    if ((threadIdx.x & 63) == 0) { rs[w] = s; rp[w] = p; }
    __syncthreads();
    if (threadIdx.x == 0) {
        const double S = rs[0] + rs[1] + rs[2] + rs[3];
        const double P = rp[0] + rp[1] + rp[2] + rp[3];
        const double rank = (S - (double)NN * (double)MARGIN)
                          / ((double)NN * (double)(NN - 1));
        out[0] = (float)(0.5 * (P / (double)NN) + 0.5 * rank);
    }
}

extern "C" void kernel_launch(void* const* d_in, const int* in_sizes, int n_in,
                              void* d_out, int out_size, void* d_ws, size_t ws_size,
                              hipStream_t stream)
{
    const float* pred = (const float*)d_in[0];
    const float* act  = (const float*)d_in[1];
    const float* prev = (const float*)d_in[2];

    double* partials = (double*)d_ws;   // NBLOCKS * 2 * 8 = 16896 bytes

    pair_kernel<<<NBLOCKS, TI, 0, stream>>>(pred, act, prev, partials);
    finalize_kernel<<<1, 256, 0, stream>>>(partials, (float*)d_out);
}

// Round 6
// 14.746 us; speedup vs baseline: 4.3666x; 1.0637x over previous
//
#include <hip/hip_runtime.h>

constexpr int    NN     = 8192;
constexpr float  MARGIN = 0.01f;
constexpr int    BT     = 256;           // threads per block
constexpr int    FI     = 4;             // i-rows per thread
constexpr int    TI     = BT * FI;       // 1024 i-rows per block
constexpr int    TJ     = 32;            // j-chunk per block
constexpr int    NTI    = NN / TI;       // 8
constexpr int    NTJ    = NN / TJ;       // 256
// row ib: jc in [32*ib, 256) -> 256-32*ib blocks; total:
constexpr int    NBLOCKS = 8 * 256 - 32 * 28;   // 1152

// Symmetry: hinge(i,j)==hinge(j,i). For i-tile ib, j-chunks with t<32 lie
// inside the 1024x1024 diagonal tile -> each ordered pair once, no doubling;
// t>=32 -> strictly upper tiles, doubled. Diagonal slots i==j contribute
// exactly MARGIN each (ad=0, pd=0); subtracted analytically in finalize.
// count = NN*(NN-1) (continuous data, no off-diag ties; validated absmax==0).
__global__ __launch_bounds__(BT)
void pair_kernel(const float* __restrict__ pred,
                 const float* __restrict__ act,
                 const float* __restrict__ prev,
                 double* __restrict__ partials)   // [NBLOCKS][2]: rank, price
{
    // decode flat block id -> (ib, t); row ib has (256 - 32*ib) j-chunks
    int t  = blockIdx.x;
    int ib = 0;
    while (t >= NTJ - 32 * ib) { t -= NTJ - 32 * ib; ++ib; }
    const int  jc        = 32 * ib + t;
    const bool diag_like = (t < 32);
    const bool do_price  = (t == 0);

    __shared__ alignas(16) float2 s_t[TJ];

    const int tid = threadIdx.x;
    if (tid < TJ) {
        const int   j   = jc * TJ + tid;
        const float pv  = prev[j];
        const float rcp = __builtin_amdgcn_rcpf(pv);
        s_t[tid] = make_float2((pred[j] - pv) * rcp, (act[j] - pv) * rcp);
    }

    // 4 i-rows per thread: ib*1024 + tid + {0,256,512,768} (coalesced)
    float pri[FI], ari[FI];
    double pp = 0.0;
#pragma unroll
    for (int f = 0; f < FI; ++f) {
        const int   i   = ib * TI + f * BT + tid;
        const float pv  = prev[i];
        const float p   = pred[i];
        const float a   = act[i];
        const float rcp = __builtin_amdgcn_rcpf(pv);
        pri[f] = (p - pv) * rcp;
        ari[f] = (a - pv) * rcp;
        if (do_price) {
            const float d = p - a;
            pp += (double)(d * d);
        }
    }

    __syncthreads();

    float acc[FI] = {0.f, 0.f, 0.f, 0.f};

#define PAIR(f, pj, aj)                                     \
    {                                                       \
        const float ad = ari[f] - (aj);                     \
        const float pd = pri[f] - (pj);                     \
        const float s  = (ad > 0.0f) ? -1.0f : 1.0f;        \
        acc[f] += fmaxf(0.0f, fmaf(s, pd, MARGIN));         \
    }

    const float4* __restrict__ s4 = (const float4*)s_t;   // 16 x (2 j's)
#pragma unroll
    for (int g = 0; g < TJ / 2; ++g) {
        const float4 q = s4[g];
        PAIR(0, q.x, q.y); PAIR(1, q.x, q.y);
        PAIR(2, q.x, q.y); PAIR(3, q.x, q.y);
        PAIR(0, q.z, q.w); PAIR(1, q.z, q.w);
        PAIR(2, q.z, q.w); PAIR(3, q.z, q.w);
    }
#undef PAIR

    double ws = (double)((acc[0] + acc[1]) + (acc[2] + acc[3]));
    if (!diag_like) ws += ws;

    // wave-64 butterfly
    for (int off = 32; off > 0; off >>= 1) {
        ws += __shfl_down(ws, off, 64);
        pp += __shfl_down(pp, off, 64);
    }

    __shared__ double rs[4], rp[4];
    const int w = tid >> 6;
    if ((tid & 63) == 0) { rs[w] = ws; rp[w] = pp; }
    __syncthreads();
    if (tid == 0) {
        partials[2 * blockIdx.x + 0] = rs[0] + rs[1] + rs[2] + rs[3];
        partials[2 * blockIdx.x + 1] = rp[0] + rp[1] + rp[2] + rp[3];
    }
}

__global__ __launch_bounds__(256)
void finalize_kernel(const double* __restrict__ partials,
                     float* __restrict__ out)
{
    double s = 0.0, p = 0.0;
    for (int t = threadIdx.x; t < NBLOCKS; t += 256) {
        s += partials[2 * t + 0];
        p += partials[2 * t + 1];
    }
    for (int off = 32; off > 0; off >>= 1) {
        s += __shfl_down(s, off, 64);
        p += __shfl_down(p, off, 64);
    }
    __shared__ double rs[4], rp[4];
    const int w = threadIdx.x >> 6;
    if ((threadIdx.x & 63) == 0) { rs[w] = s; rp[w] = p; }
    __syncthreads();
    if (threadIdx.x == 0) {
        const double S = rs[0] + rs[1] + rs[2] + rs[3];
        const double P = rp[0] + rp[1] + rp[2] + rp[3];
        const double rank = (S - (double)NN * (double)MARGIN)
                          / ((double)NN * (double)(NN - 1));
        out[0] = (float)(0.5 * (P / (double)NN) + 0.5 * rank);
    }
}

extern "C" void kernel_launch(void* const* d_in, const int* in_sizes, int n_in,
                              void* d_out, int out_size, void* d_ws, size_t ws_size,
                              hipStream_t stream)
{
    const float* pred = (const float*)d_in[0];
    const float* act  = (const float*)d_in[1];
    const float* prev = (const float*)d_in[2];

    double* partials = (double*)d_ws;   // NBLOCKS * 2 * 8 = 18432 bytes

    pair_kernel<<<NBLOCKS, BT, 0, stream>>>(pred, act, prev, partials);
    finalize_kernel<<<1, 256, 0, stream>>>(partials, (float*)d_out);
}